// Round 2
// baseline (45.937 us; speedup 1.0000x reference)
//
#include <hip/hip_runtime.h>
#include <math.h>

#define CIN   8
#define COUT  8
#define HH    16
#define NN    400
#define MM    400
#define BB    16
#define KK    64

#define THREADS 256     // 4 waves
#define GM      4       // m's per block
#define KCH     16      // k's per block (one o-pair x 8 i)
#define PMAX    32      // max inside-nodes per m (measured ~15 worst-case)

__global__ __launch_bounds__(THREADS) void quadconv_kernel(
    const float* __restrict__ f,      // (B, CIN, NN)
    const float* __restrict__ W1,     // (K, H, 2)
    const float* __restrict__ W2,     // (K, H, H)
    const float* __restrict__ W3,     // (K, 1, H)
    const float* __restrict__ locs,   // (MM, 2)
    const float* __restrict__ nodes,  // (NN, 2)
    const float* __restrict__ wq,     // (NN,)
    float* __restrict__ out)          // (B, COUT, MM)
{
    __shared__ int   s_pn[GM][PMAX];
    __shared__ float s_pzx[GM][PMAX];
    __shared__ float s_pzy[GM][PMAX];
    __shared__ float s_pbw[GM][PMAX];
    __shared__ int   s_cnt[GM];
    __shared__ float s_kvs[128 * (KCH + 1)];   // [pair][k_local], stride 17
    __shared__ float s_red[4][32][GM];

    const int t    = threadIdx.x;
    const int lane = t & 63;
    const int w    = t >> 6;
    const int mg   = blockIdx.x >> 2;      // m-group
    const int kq   = blockIdx.x & 3;       // k-quarter
    const int m0   = mg * GM;

    // ---------------- Phase A: per-m compaction (wave w handles m0+w) -------
    {
        const float2* lc = (const float2*)locs;
        const float2* nd = (const float2*)nodes;
        float2 y = lc[m0 + w];
        int cntw = 0;
        for (int n0 = 0; n0 < NN; n0 += 64) {
            int n = n0 + lane;
            bool in = false;
            float zx = 0.f, zy = 0.f, bw = 0.f;
            if (n < NN) {
                float2 x = nd[n];
                zx = y.x - x.x; zy = y.y - x.y;
                float s = zx*zx + zy*zy;
                float a = s * s;                 // ||z||^4
                if (a < (1.0f/625.0f)) {
                    in = true;
                    bw = __expf(1.0f - 1.0f/(1.0f - 625.0f*a)) * wq[n];
                }
            }
            unsigned long long msk = __ballot(in);
            int before = __popcll(msk & ((1ull << lane) - 1ull));
            if (in) {
                int s = cntw + before;
                if (s < PMAX) {
                    s_pn[w][s] = n; s_pzx[w][s] = zx;
                    s_pzy[w][s] = zy; s_pbw[w][s] = bw;
                }
            }
            cntw += __popcll(msk);
        }
        if (lane == 0) s_cnt[w] = min(cntw, PMAX);
    }
    __syncthreads();

    const int c0 = s_cnt[0], c1 = s_cnt[1], c2 = s_cnt[2], c3 = s_cnt[3];
    const int o1 = c0, o2 = c0 + c1, o3 = c0 + c1 + c2;
    const int cnt_tot = o3 + c3;          // <= 128

    // ---------------- Phase B: MLP eval, lane = flat pair, k wave-uniform ---
    {
        const int kw = __builtin_amdgcn_readfirstlane(w);   // force SGPR k
        const int PP = (cnt_tot + 63) >> 6;
        for (int pp = 0; pp < PP; ++pp) {
            int p = pp * 64 + lane;
            bool valid = p < cnt_tot;
            int ms = 0, off = 0;
            if (p >= o1) { ms = 1; off = o1; }
            if (p >= o2) { ms = 2; off = o2; }
            if (p >= o3) { ms = 3; off = o3; }
            int j = valid ? (p - off) : 0;
            if (!valid) ms = 0;
            float zx = s_pzx[ms][j], zy = s_pzy[ms][j];
            float bw = valid ? s_pbw[ms][j] : 0.f;

            #pragma unroll
            for (int kk = 0; kk < 4; ++kk) {
                const int kl = kw * 4 + kk;            // k local (0..15)
                const int k  = kq * KCH + kl;          // global k
                const float* __restrict__ w1 = W1 + k * (HH * 2);
                const float* __restrict__ w2 = W2 + k * (HH * HH);
                const float* __restrict__ w3 = W3 + k * HH;
                float h1[HH];
                #pragma unroll
                for (int jj = 0; jj < HH; ++jj)
                    h1[jj] = __sinf(w1[2*jj] * zx + w1[2*jj + 1] * zy);
                float kv = 0.f;
                #pragma unroll
                for (int oo = 0; oo < HH; ++oo) {
                    float d = 0.f;
                    #pragma unroll
                    for (int jj = 0; jj < HH; ++jj)
                        d += w2[oo*HH + jj] * h1[jj];
                    kv += w3[oo] * __sinf(d);
                }
                s_kvs[p * (KCH + 1) + kl] = kv * bw;
            }
        }
    }
    __syncthreads();

    // ---------------- Phase C: contraction, 256 threads = (b,o_loc,i) ------
    // out[b, kq*2+ol, m0+ms] = sum over pairs, i of kv * f
    {
        const int b  = t & 15;
        const int ol = (t >> 4) & 1;
        const int ii = t >> 5;             // 0..7 (single input channel)
        const float* __restrict__ fb = f + b * (CIN * NN) + ii * NN;
        const int kvoff = ol * 8 + ii;

        float acc[GM];
        int base = 0;
        #pragma unroll
        for (int ms = 0; ms < GM; ++ms) {
            float a = 0.f;
            int cm = s_cnt[ms];
            for (int j = 0; j < cm; ++j) {
                int p = base + j;
                float kv = s_kvs[p * (KCH + 1) + kvoff];
                int  n  = s_pn[ms][j];
                a += kv * fb[n];
            }
            acc[ms] = a;
            base += cm;
        }

        // reduce over i: bit0 of ii is lane^32 (in-wave), bits1-2 are wave id
        #pragma unroll
        for (int ms = 0; ms < GM; ++ms)
            acc[ms] += __shfl_xor(acc[ms], 32);
        if (lane < 32) {
            #pragma unroll
            for (int ms = 0; ms < GM; ++ms)
                s_red[w][lane][ms] = acc[ms];
        }
    }
    __syncthreads();

    if (t < 32) {
        const int b = t & 15, ol = t >> 4;
        #pragma unroll
        for (int ms = 0; ms < GM; ++ms) {
            float v = s_red[0][t][ms] + s_red[1][t][ms]
                    + s_red[2][t][ms] + s_red[3][t][ms];
            out[b * (COUT*MM) + (kq*2 + ol) * MM + (m0 + ms)] = v;
        }
    }
}

extern "C" void kernel_launch(void* const* d_in, const int* in_sizes, int n_in,
                              void* d_out, int out_size, void* d_ws, size_t ws_size,
                              hipStream_t stream) {
    const float* f     = (const float*)d_in[0];
    const float* W1    = (const float*)d_in[1];
    const float* W2    = (const float*)d_in[2];
    const float* W3    = (const float*)d_in[3];
    const float* locs  = (const float*)d_in[4];
    const float* nodes = (const float*)d_in[5];
    const float* wq    = (const float*)d_in[6];
    float* out = (float*)d_out;

    // 400 blocks: 100 m-groups x 4 k-quarters
    quadconv_kernel<<<dim3((MM/GM) * 4), dim3(THREADS), 0, stream>>>(
        f, W1, W2, W3, locs, nodes, wq, out);
}

// Round 4
// 36.818 us; speedup vs baseline: 1.2477x; 1.2477x over previous
//
#include <hip/hip_runtime.h>
#include <math.h>

#define CIN   8
#define COUT  8
#define HH    16
#define NN    400
#define MM    400
#define BB    16

#define THREADS 512    // 8 waves
#define GM      2      // m's per block
#define PMAX    32     // padded slots per m (worst-case inside count ~24)

// grid = (MM/GM) * COUT = 200 * 8 = 1600 blocks
// block (pg, kg): m in [pg*2, pg*2+2), output channel o = kg.
// wave w (0..7): k = kg*8 + w  ->  o = kg, i = w. Weights wave-uniform (SGPR).
// phase B: lane = slot (2 m's x 32 padded pair-slots).

__global__ __launch_bounds__(THREADS, 8) void quadconv_kernel(
    const float* __restrict__ f,      // (B, CIN, NN)
    const float* __restrict__ W1,     // (K, H, 2)
    const float* __restrict__ W2,     // (K, H, H)
    const float* __restrict__ W3,     // (K, 1, H)
    const float* __restrict__ locs,   // (MM, 2)
    const float* __restrict__ nodes,  // (NN, 2)
    const float* __restrict__ wq,     // (NN,)
    float* __restrict__ out)          // (B, COUT, MM)
{
    __shared__ float s_zx[GM*PMAX];
    __shared__ float s_zy[GM*PMAX];
    __shared__ float s_bw[GM*PMAX];
    __shared__ int   s_pn[GM*PMAX];
    __shared__ float s_kv[8*64];      // [wave][slot]
    __shared__ float s_part[8*32];    // [wave][g*16+b]

    const int t    = threadIdx.x;
    const int lane = t & 63;
    const int w    = __builtin_amdgcn_readfirstlane(t >> 6);
    const int pg   = blockIdx.x >> 3;
    const int kg   = blockIdx.x & 7;
    const int m0   = pg * GM;

    // ---- Phase A: waves 0-1 build padded inside-lists for m0+w ----
    if (w < GM) {
        const float2 y = ((const float2*)locs)[m0 + w];
        const float2* nd = (const float2*)nodes;
        int cnt = 0;
        for (int n0 = 0; n0 < NN; n0 += 64) {
            int n = n0 + lane;
            bool in = false;
            float zx = 0.f, zy = 0.f, bw = 0.f;
            if (n < NN) {
                float2 x = nd[n];
                zx = y.x - x.x; zy = y.y - x.y;
                float s = zx*zx + zy*zy;
                float a = s * s;                    // ||z||^4
                if (a < (1.0f/625.0f)) {
                    in = true;
                    bw = __expf(1.0f - 1.0f/(1.0f - 625.0f*a)) * wq[n];
                }
            }
            unsigned long long msk = __ballot(in);
            int idx = cnt + __popcll(msk & ((1ull << lane) - 1ull));
            if (in && idx < PMAX) {
                s_pn[w*PMAX + idx] = n;
                s_zx[w*PMAX + idx] = zx;
                s_zy[w*PMAX + idx] = zy;
                s_bw[w*PMAX + idx] = bw;
            }
            cnt += __popcll(msk);
        }
        // zero-fill pad slots (bw=0 -> exact zero contribution)
        if (lane >= cnt && lane < PMAX) {
            s_pn[w*PMAX + lane] = 0;
            s_zx[w*PMAX + lane] = 0.f;
            s_zy[w*PMAX + lane] = 0.f;
            s_bw[w*PMAX + lane] = 0.f;
        }
    }
    __syncthreads();

    // ---- Phase B: per-wave MLP, k wave-uniform, lane = slot ----
    {
        const int k = kg * 8 + w;
        const float* __restrict__ w1 = W1 + k * (HH * 2);
        const float* __restrict__ w2 = W2 + k * (HH * HH);
        const float* __restrict__ w3 = W3 + k * HH;

        const float zx = s_zx[lane], zy = s_zy[lane], bw = s_bw[lane];

        float h1[HH];
        #pragma unroll
        for (int j = 0; j < HH; ++j)
            h1[j] = __sinf(w1[2*j] * zx + w1[2*j + 1] * zy);

        float kv = 0.f;
        #pragma unroll
        for (int oo = 0; oo < HH; ++oo) {
            float d = 0.f;
            #pragma unroll
            for (int j = 0; j < HH; ++j)
                d += w2[oo*HH + j] * h1[j];
            kv += w3[oo] * __sinf(d);
        }
        s_kv[w*64 + lane] = kv * bw;
    }

    // ---- Phase C: contraction. lane = (half, g, b); 16 j-terms per lane ----
    {
        const int b    = lane & 15;
        const int g    = (lane >> 4) & 1;
        const int half = lane >> 5;
        const float* __restrict__ fb = f + b * (CIN*NN) + w * NN;   // i = w
        float acc = 0.f;
        #pragma unroll
        for (int jj = 0; jj < PMAX/2; ++jj) {
            int   j  = half * (PMAX/2) + jj;
            int   n  = s_pn[g*PMAX + j];
            float kv = s_kv[w*64 + g*PMAX + j];
            acc += kv * fb[n];
        }
        acc += __shfl_xor(acc, 32);       // combine the two halves
        if (half == 0)
            s_part[w*32 + lane] = acc;    // lane = g*16 + b
    }
    __syncthreads();

    // ---- Final: sum over i (=wave) and store ----
    if (t < 32) {
        const int b = t & 15, g = t >> 4;
        float v = 0.f;
        #pragma unroll
        for (int ww = 0; ww < 8; ++ww)
            v += s_part[ww*32 + t];
        out[b * (COUT*MM) + kg * MM + (m0 + g)] = v;
    }
}

extern "C" void kernel_launch(void* const* d_in, const int* in_sizes, int n_in,
                              void* d_out, int out_size, void* d_ws, size_t ws_size,
                              hipStream_t stream) {
    const float* f     = (const float*)d_in[0];
    const float* W1    = (const float*)d_in[1];
    const float* W2    = (const float*)d_in[2];
    const float* W3    = (const float*)d_in[3];
    const float* locs  = (const float*)d_in[4];
    const float* nodes = (const float*)d_in[5];
    const float* wq    = (const float*)d_in[6];
    float* out = (float*)d_out;

    quadconv_kernel<<<dim3((MM/GM) * COUT), dim3(THREADS), 0, stream>>>(
        f, W1, W2, W3, locs, nodes, wq, out);
}

// Round 5
// 23.555 us; speedup vs baseline: 1.9502x; 1.5631x over previous
//
#include <hip/hip_runtime.h>
#include <math.h>

#define CIN   8
#define COUT  8
#define HH    16
#define NN    400
#define MM    400
#define BB    16

#define THREADS 512    // 8 waves
#define GM      2      // m's per block (main kernel)
#define PMAX    32     // padded slots per m (worst-case inside count ~26)

// ws layout (floats):
//   ft[NN*CIN*BB]   : ft[n*128 + i*16 + b] = f[b][i][n]
//   zx[MM*PMAX], zy[MM*PMAX], bw[MM*PMAX], pn[MM*PMAX] (int)
#define WS_FT 0
#define WS_ZX (NN*CIN*BB)
#define WS_ZY (WS_ZX + MM*PMAX)
#define WS_BW (WS_ZY + MM*PMAX)
#define WS_PN (WS_BW + MM*PMAX)

// ---------------- kernel 1: feature transpose + inside-lists ----------------
__global__ __launch_bounds__(THREADS) void prep_kernel(
    const float* __restrict__ f,      // (B, CIN, NN)
    const float* __restrict__ locs,   // (MM, 2)
    const float* __restrict__ nodes,  // (NN, 2)
    const float* __restrict__ wq,     // (NN,)
    float* __restrict__ ws)
{
    const int blk = blockIdx.x;
    const int t   = threadIdx.x;

    if (blk < 100) {
        // transpose: 100 blocks x 512 threads = 51200 elements
        int idx = blk * 512 + t;          // = n*128 + i*16 + b
        int n = idx >> 7, c = idx & 127;
        int i = c >> 4, b = c & 15;
        ws[WS_FT + idx] = f[b * (CIN*NN) + i * NN + n];
    } else {
        // inside-lists: 50 blocks x 8 waves, one m per wave
        const int lane = t & 63;
        const int w    = t >> 6;
        const int m    = (blk - 100) * 8 + w;
        const float2 y = ((const float2*)locs)[m];
        const float2* nd = (const float2*)nodes;
        int cnt = 0;
        for (int n0 = 0; n0 < NN; n0 += 64) {
            int n = n0 + lane;
            bool in = false;
            float zx = 0.f, zy = 0.f, bwv = 0.f;
            if (n < NN) {
                float2 x = nd[n];
                zx = y.x - x.x; zy = y.y - x.y;
                float s = zx*zx + zy*zy;
                float a = s * s;                    // ||z||^4
                if (a < (1.0f/625.0f)) {
                    in = true;
                    bwv = __expf(1.0f - 1.0f/(1.0f - 625.0f*a)) * wq[n];
                }
            }
            unsigned long long msk = __ballot(in);
            int idx = cnt + __popcll(msk & ((1ull << lane) - 1ull));
            if (in && idx < PMAX) {
                ws[WS_ZX + m*PMAX + idx] = zx;
                ws[WS_ZY + m*PMAX + idx] = zy;
                ws[WS_BW + m*PMAX + idx] = bwv;
                ((int*)ws)[WS_PN + m*PMAX + idx] = n;
            }
            cnt += __popcll(msk);
        }
        // zero-fill pad slots (bw=0 -> exact zero contribution)
        if (lane >= cnt && lane < PMAX) {
            ws[WS_ZX + m*PMAX + lane] = 0.f;
            ws[WS_ZY + m*PMAX + lane] = 0.f;
            ws[WS_BW + m*PMAX + lane] = 0.f;
            ((int*)ws)[WS_PN + m*PMAX + lane] = 0;
        }
    }
}

// ---------------- kernel 2: MLP eval + contraction ----------------
// grid = (MM/GM) * COUT = 200 * 8 = 1600 blocks
// block (pg, kg): m in [pg*2, pg*2+2), output channel o = kg.
// wave w (0..7): k = kg*8 + w  ->  o = kg, i = w. Weights wave-uniform (SGPR).
__global__ __launch_bounds__(THREADS, 8) void quadconv_kernel(
    const float* __restrict__ W1,     // (K, H, 2)
    const float* __restrict__ W2,     // (K, H, H)
    const float* __restrict__ W3,     // (K, 1, H)
    const float* __restrict__ ws,     // ft + lists
    float* __restrict__ out)          // (B, COUT, MM)
{
    __shared__ float s_kv[8*64];      // [wave][slot]
    __shared__ float s_part[8*32];    // [wave][g*16+b]
    __shared__ int   s_pn[GM*PMAX];   // 64 node ids

    const int t    = threadIdx.x;
    const int lane = t & 63;
    const int w    = __builtin_amdgcn_readfirstlane(t >> 6);
    const int pg   = blockIdx.x >> 3;
    const int kg   = blockIdx.x & 7;
    const int m0   = pg * GM;

    // lane = slot (2 m's x 32 padded slots); coalesced list loads
    const float zx = ws[WS_ZX + m0*PMAX + lane];
    const float zy = ws[WS_ZY + m0*PMAX + lane];
    const float bw = ws[WS_BW + m0*PMAX + lane];
    if (t < GM*PMAX) s_pn[t] = ((const int*)ws)[WS_PN + m0*PMAX + t];

    // ---- Phase B: per-wave MLP, k wave-uniform, lane = slot ----
    {
        const int k = kg * 8 + w;
        const float* __restrict__ w1 = W1 + k * (HH * 2);
        const float* __restrict__ w2 = W2 + k * (HH * HH);
        const float* __restrict__ w3 = W3 + k * HH;

        float h1[HH];
        #pragma unroll
        for (int j = 0; j < HH; ++j)
            h1[j] = __sinf(w1[2*j] * zx + w1[2*j + 1] * zy);

        float kv = 0.f;
        #pragma unroll
        for (int oo = 0; oo < HH; ++oo) {
            float d = 0.f;
            #pragma unroll
            for (int j = 0; j < HH; ++j)
                d += w2[oo*HH + j] * h1[j];
            kv += w3[oo] * __sinf(d);
        }
        s_kv[w*64 + lane] = kv * bw;
    }
    __syncthreads();

    // ---- Phase C: contraction on transposed features ----
    // lane = (half, g, b); 16 j-terms per lane; ft loads are 4x64B per instr
    {
        const int b    = lane & 15;
        const int g    = (lane >> 4) & 1;
        const int half = lane >> 5;
        const float* __restrict__ ftp = ws + WS_FT;
        float acc = 0.f;
        #pragma unroll
        for (int jj = 0; jj < PMAX/2; ++jj) {
            int   sl = g*PMAX + half*(PMAX/2) + jj;
            int   n  = s_pn[sl];
            float kv = s_kv[w*64 + sl];
            acc += kv * ftp[n*128 + w*16 + b];   // i = w
        }
        acc += __shfl_xor(acc, 32);       // combine the two halves
        if (half == 0)
            s_part[w*32 + lane] = acc;    // lane = g*16 + b
    }
    __syncthreads();

    // ---- Final: sum over i (=wave) and store ----
    if (t < 32) {
        const int b = t & 15, g = t >> 4;
        float v = 0.f;
        #pragma unroll
        for (int ww = 0; ww < 8; ++ww)
            v += s_part[ww*32 + t];
        out[b * (COUT*MM) + kg * MM + (m0 + g)] = v;
    }
}

extern "C" void kernel_launch(void* const* d_in, const int* in_sizes, int n_in,
                              void* d_out, int out_size, void* d_ws, size_t ws_size,
                              hipStream_t stream) {
    const float* f     = (const float*)d_in[0];
    const float* W1    = (const float*)d_in[1];
    const float* W2    = (const float*)d_in[2];
    const float* W3    = (const float*)d_in[3];
    const float* locs  = (const float*)d_in[4];
    const float* nodes = (const float*)d_in[5];
    const float* wq    = (const float*)d_in[6];
    float* out = (float*)d_out;
    float* ws  = (float*)d_ws;

    prep_kernel<<<dim3(150), dim3(THREADS), 0, stream>>>(f, locs, nodes, wq, ws);
    quadconv_kernel<<<dim3((MM/GM) * COUT), dim3(THREADS), 0, stream>>>(
        W1, W2, W3, ws, out);
}